// Round 1
// baseline (969.650 us; speedup 1.0000x reference)
//
#include <hip/hip_runtime.h>
#include <math.h>

#define N_NODES  50000
#define N_EDGES  800000
#define N_GRAPHS 5000
#define N_PAIRS  4096
#define F_IN     9
#define H        64

// ---------------- degree / norm / counts ----------------

__global__ void k_deg(const int* __restrict__ dst, float* __restrict__ deg) {
    int e = blockIdx.x * blockDim.x + threadIdx.x;
    if (e < N_EDGES) atomicAdd(&deg[dst[e]], 1.0f);
}

__global__ void k_dis(const float* __restrict__ deg, float* __restrict__ dis) {
    int i = blockIdx.x * blockDim.x + threadIdx.x;
    if (i < N_NODES) dis[i] = rsqrtf(deg[i] + 1.0f);
}

__global__ void k_cnt(const int* __restrict__ batch, float* __restrict__ cnt) {
    int i = blockIdx.x * blockDim.x + threadIdx.x;
    if (i < N_NODES) atomicAdd(&cnt[batch[i]], 1.0f);
}

// ---------------- dense matmuls ----------------

// x (N,9) @ W (9,64) -> hw (N,64). 4 rows per 256-block, lane j = out col.
__global__ void k_mm_in(const float* __restrict__ x, const float* __restrict__ W,
                        float* __restrict__ hw) {
    __shared__ float sW[F_IN * H];
    for (int t = threadIdx.x; t < F_IN * H; t += 256) sW[t] = W[t];
    __syncthreads();
    int row = blockIdx.x * 4 + (threadIdx.x >> 6);
    int j   = threadIdx.x & 63;
    if (row < N_NODES) {
        float acc = 0.f;
#pragma unroll
        for (int k = 0; k < F_IN; ++k) acc += x[row * F_IN + k] * sW[k * H + j];
        hw[row * H + j] = acc;
    }
}

// h (N,64) @ W (64,64) -> hw (N,64). 4 rows per 256-block.
__global__ void k_mm_h(const float* __restrict__ h, const float* __restrict__ W,
                       float* __restrict__ hw) {
    __shared__ float sW[H * H];
    __shared__ float srow[4][H];
    for (int t = threadIdx.x; t < H * H; t += 256) sW[t] = W[t];
    int wi = threadIdx.x >> 6;
    int j  = threadIdx.x & 63;
    int row = blockIdx.x * 4 + wi;
    if (row < N_NODES) srow[wi][j] = h[row * H + j];
    __syncthreads();
    if (row < N_NODES) {
        float acc = 0.f;
#pragma unroll
        for (int k = 0; k < H; ++k) acc += srow[wi][k] * sW[k * H + j];
        hw[row * H + j] = acc;
    }
}

// ---------------- GCN aggregate ----------------

// agg[i][j] = hw[i][j] * dis[i]^2   (self-loop term; fully initializes agg)
__global__ void k_self(const float* __restrict__ hw, const float* __restrict__ dis,
                       float* __restrict__ agg) {
    int idx = blockIdx.x * blockDim.x + threadIdx.x;
    if (idx < N_NODES * H) {
        int i = idx >> 6;
        float d = dis[i];
        agg[idx] = hw[idx] * d * d;
    }
}

// edge scatter: agg[dst] += hw[src] * dis[src]*dis[dst]; one wave per edge.
__global__ void k_scatter(const int* __restrict__ src, const int* __restrict__ dst,
                          const float* __restrict__ dis, const float* __restrict__ hw,
                          float* __restrict__ agg) {
    int e = blockIdx.x * 4 + (threadIdx.x >> 6);
    int j = threadIdx.x & 63;
    if (e < N_EDGES) {
        int s = src[e], d = dst[e];
        float norm = dis[s] * dis[d];
        atomicAdd(&agg[d * H + j], hw[s * H + j] * norm);
    }
}

__global__ void k_bias_tanh(const float* __restrict__ agg, const float* __restrict__ b,
                            float* __restrict__ h) {
    int idx = blockIdx.x * blockDim.x + threadIdx.x;
    if (idx < N_NODES * H) h[idx] = tanhf(agg[idx] + b[idx & 63]);
}

// ---------------- fused MLP + graph pool ----------------

__global__ void k_mlp(const float* __restrict__ h, const int* __restrict__ batch,
                      const float* __restrict__ fc1w, const float* __restrict__ fc1b,
                      const float* __restrict__ fc2w, const float* __restrict__ fc2b,
                      const float* __restrict__ fc3w, const float* __restrict__ fc3b,
                      float* __restrict__ sums) {
    __shared__ float s1[H * H];     // 16 KB
    __shared__ float s2[H * 32];    // 8 KB
    __shared__ float s3[32];
    __shared__ float sb1[H];
    __shared__ float sb2[32];
    __shared__ float srow[4][H];
    __shared__ float s1out[4][H];

    for (int t = threadIdx.x; t < H * H; t += 256) s1[t] = fc1w[t];
    for (int t = threadIdx.x; t < H * 32; t += 256) s2[t] = fc2w[t];
    if (threadIdx.x < 32) s3[threadIdx.x] = fc3w[threadIdx.x];
    if (threadIdx.x < H)  sb1[threadIdx.x] = fc1b[threadIdx.x];
    if (threadIdx.x < 32) sb2[threadIdx.x] = fc2b[threadIdx.x];
    __syncthreads();

    int wi   = threadIdx.x >> 6;
    int j    = threadIdx.x & 63;
    int node = blockIdx.x * 4 + wi;
    if (node >= N_NODES) return;

    srow[wi][j] = h[node * H + j];   // wave-local write+read: in-order per wave

    float a1 = 0.f;
#pragma unroll
    for (int k = 0; k < H; ++k) a1 += srow[wi][k] * s1[k * H + j];
    a1 = tanhf(a1 + sb1[j]);
    s1out[wi][j] = a1;

    float a2 = 0.f;
    if (j < 32) {
#pragma unroll
        for (int k = 0; k < H; ++k) a2 += s1out[wi][k] * s2[k * 32 + j];
        a2 = tanhf(a2 + sb2[j]);
        a2 *= s3[j];                 // fold fc3 weight into the reduce
    }
    // reduce fc3 dot over lanes 0..31
    for (int off = 16; off > 0; off >>= 1) a2 += __shfl_down(a2, off, 32);
    if (j == 0) {
        float val = a2 + fc3b[0];
        atomicAdd(&sums[batch[node]], val);
    }
}

// ---------------- readout ----------------

__global__ void k_util(const float* __restrict__ sums, const float* __restrict__ cnt,
                       float* __restrict__ out_util) {
    int g = blockIdx.x * blockDim.x + threadIdx.x;
    if (g < N_GRAPHS) out_util[g] = sums[g] / fmaxf(cnt[g], 1.0f);
}

__global__ void k_pairs(const float* __restrict__ u, const int* __restrict__ ia,
                        const int* __restrict__ ib, float* __restrict__ out) {
    int p = blockIdx.x * blockDim.x + threadIdx.x;
    if (p < N_PAIRS) {
        float d = u[ib[p]] - u[ia[p]];
        out[p] = 1.0f / (1.0f + expf(-d));
    }
}

// ---------------- launch ----------------

extern "C" void kernel_launch(void* const* d_in, const int* in_sizes, int n_in,
                              void* d_out, int out_size, void* d_ws, size_t ws_size,
                              hipStream_t stream) {
    const float* x     = (const float*)d_in[0];
    const int*   ei    = (const int*)d_in[1];
    const int*   batch = (const int*)d_in[2];
    const int*   idx_a = (const int*)d_in[3];
    const int*   idx_b = (const int*)d_in[4];
    const float* W_in  = (const float*)d_in[5];
    const float* b_in  = (const float*)d_in[6];
    const float* W_h   = (const float*)d_in[7];
    const float* b_h   = (const float*)d_in[8];
    const float* W_out = (const float*)d_in[9];
    const float* b_out = (const float*)d_in[10];
    const float* fc1_w = (const float*)d_in[11];
    const float* fc1_b = (const float*)d_in[12];
    const float* fc2_w = (const float*)d_in[13];
    const float* fc2_b = (const float*)d_in[14];
    const float* fc3_w = (const float*)d_in[15];
    const float* fc3_b = (const float*)d_in[16];

    const int* src = ei;
    const int* dst = ei + N_EDGES;

    float* ws   = (float*)d_ws;
    float* deg  = ws;  ws += N_NODES;
    float* dis  = ws;  ws += N_NODES;
    float* cnt  = ws;  ws += N_GRAPHS;
    float* sums = ws;  ws += N_GRAPHS;
    float* hw   = ws;  ws += (size_t)N_NODES * H;
    float* agg  = ws;  ws += (size_t)N_NODES * H;
    float* h    = ws;  ws += (size_t)N_NODES * H;

    float* out_pairs = (float*)d_out;
    float* out_util  = out_pairs + N_PAIRS;

    hipMemsetAsync(deg,  0, N_NODES  * sizeof(float), stream);
    hipMemsetAsync(cnt,  0, N_GRAPHS * sizeof(float), stream);
    hipMemsetAsync(sums, 0, N_GRAPHS * sizeof(float), stream);

    dim3 blk(256);
    k_deg<<<(N_EDGES + 255) / 256, blk, 0, stream>>>(dst, deg);
    k_dis<<<(N_NODES + 255) / 256, blk, 0, stream>>>(deg, dis);
    k_cnt<<<(N_NODES + 255) / 256, blk, 0, stream>>>(batch, cnt);

    const int row_blocks  = (N_NODES + 3) / 4;
    const int elem_blocks = (N_NODES * H + 255) / 256;
    const int edge_blocks = (N_EDGES + 3) / 4;

    // layer 1 (F_IN -> H)
    k_mm_in<<<row_blocks, blk, 0, stream>>>(x, W_in, hw);
    k_self<<<elem_blocks, blk, 0, stream>>>(hw, dis, agg);
    k_scatter<<<edge_blocks, blk, 0, stream>>>(src, dst, dis, hw, agg);
    k_bias_tanh<<<elem_blocks, blk, 0, stream>>>(agg, b_in, h);

    // layers 2..3 (H -> H, shared weights)
    for (int l = 0; l < 2; ++l) {
        k_mm_h<<<row_blocks, blk, 0, stream>>>(h, W_h, hw);
        k_self<<<elem_blocks, blk, 0, stream>>>(hw, dis, agg);
        k_scatter<<<edge_blocks, blk, 0, stream>>>(src, dst, dis, hw, agg);
        k_bias_tanh<<<elem_blocks, blk, 0, stream>>>(agg, b_h, h);
    }

    // layer 4 (H -> H, W_out)
    k_mm_h<<<row_blocks, blk, 0, stream>>>(h, W_out, hw);
    k_self<<<elem_blocks, blk, 0, stream>>>(hw, dis, agg);
    k_scatter<<<edge_blocks, blk, 0, stream>>>(src, dst, dis, hw, agg);
    k_bias_tanh<<<elem_blocks, blk, 0, stream>>>(agg, b_out, h);

    // MLP + pool
    k_mlp<<<row_blocks, blk, 0, stream>>>(h, batch, fc1_w, fc1_b, fc2_w, fc2_b,
                                          fc3_w, fc3_b, sums);
    k_util<<<(N_GRAPHS + 255) / 256, blk, 0, stream>>>(sums, cnt, out_util);
    k_pairs<<<(N_PAIRS + 255) / 256, blk, 0, stream>>>(out_util, idx_a, idx_b, out_pairs);
}

// Round 2
// 430.929 us; speedup vs baseline: 2.2501x; 2.2501x over previous
//
#include <hip/hip_runtime.h>
#include <math.h>

#define N_NODES  50000
#define N_EDGES  800000
#define N_GRAPHS 5000
#define N_PAIRS  4096
#define F_IN     9
#define H        64
#define NCHUNK   49   // ceil(50000/1024)

// ---------------- degree / norm / counts ----------------

__global__ void k_deg(const int* __restrict__ dst, int* __restrict__ degi) {
    int e = blockIdx.x * blockDim.x + threadIdx.x;
    if (e < N_EDGES) atomicAdd(&degi[dst[e]], 1);
}

__global__ void k_dis(const int* __restrict__ degi, float* __restrict__ dis) {
    int i = blockIdx.x * blockDim.x + threadIdx.x;
    if (i < N_NODES) dis[i] = rsqrtf((float)degi[i] + 1.0f);
}

__global__ void k_cnt(const int* __restrict__ batch, float* __restrict__ cnt) {
    int i = blockIdx.x * blockDim.x + threadIdx.x;
    if (i < N_NODES) atomicAdd(&cnt[batch[i]], 1.0f);
}

// ---------------- CSR build: scan + fill ----------------

// chunk = 1024 elements; grid NCHUNK, block 256 (4 elems/thread)
__global__ void k_chunksum(const int* __restrict__ degi, int* __restrict__ chunksum) {
    __shared__ int wsum[4];
    int t = threadIdx.x, lane = t & 63, wi = t >> 6;
    int base_i = blockIdx.x * 1024 + t * 4;
    int s = 0;
#pragma unroll
    for (int k = 0; k < 4; ++k) {
        int i = base_i + k;
        if (i < N_NODES) s += degi[i];
    }
    for (int o = 32; o > 0; o >>= 1) s += __shfl_down(s, o, 64);
    if (lane == 0) wsum[wi] = s;
    __syncthreads();
    if (t == 0) chunksum[blockIdx.x] = wsum[0] + wsum[1] + wsum[2] + wsum[3];
}

// single wave: exclusive scan of NCHUNK chunk sums
__global__ void k_scanchunks(const int* __restrict__ chunksum, int* __restrict__ chunkbase,
                             int* __restrict__ off) {
    int lane = threadIdx.x;
    int v = (lane < NCHUNK) ? chunksum[lane] : 0;
    int inc = v;
    for (int o = 1; o < 64; o <<= 1) {
        int u = __shfl_up(inc, o, 64);
        if (lane >= o) inc += u;
    }
    if (lane < NCHUNK) chunkbase[lane] = inc - v;
    if (lane == 0) off[N_NODES] = N_EDGES;
}

// per-chunk exclusive scan + chunk base -> offsets & cursors
__global__ void k_scan(const int* __restrict__ degi, const int* __restrict__ chunkbase,
                       int* __restrict__ off, int* __restrict__ cur) {
    __shared__ int wsum[4];
    int t = threadIdx.x, lane = t & 63, wi = t >> 6;
    int base_i = blockIdx.x * 1024 + t * 4;
    int v[4];
    int s = 0;
#pragma unroll
    for (int k = 0; k < 4; ++k) {
        int i = base_i + k;
        v[k] = (i < N_NODES) ? degi[i] : 0;
        s += v[k];
    }
    int inc = s;
    for (int o = 1; o < 64; o <<= 1) {
        int u = __shfl_up(inc, o, 64);
        if (lane >= o) inc += u;
    }
    if (lane == 63) wsum[wi] = inc;
    __syncthreads();
    int wbase = 0;
    for (int w = 0; w < 4; ++w) if (w < wi) wbase += wsum[w];
    int ex = chunkbase[blockIdx.x] + wbase + inc - s;
#pragma unroll
    for (int k = 0; k < 4; ++k) {
        int i = base_i + k;
        if (i < N_NODES) { off[i] = ex; cur[i] = ex; }
        ex += v[k];
    }
}

__global__ void k_fill(const int* __restrict__ src, const int* __restrict__ dst,
                       const float* __restrict__ dis, int* __restrict__ cur,
                       int* __restrict__ csr_src, float* __restrict__ csr_norm) {
    int e = blockIdx.x * blockDim.x + threadIdx.x;
    if (e < N_EDGES) {
        int s = src[e], d = dst[e];
        int pos = atomicAdd(&cur[d], 1);
        csr_src[pos] = s;
        csr_norm[pos] = dis[s] * dis[d];
    }
}

// ---------------- dense matmuls ----------------

__global__ void k_mm_in(const float* __restrict__ x, const float* __restrict__ W,
                        float* __restrict__ hw) {
    __shared__ float sW[F_IN * H];
    for (int t = threadIdx.x; t < F_IN * H; t += 256) sW[t] = W[t];
    __syncthreads();
    int row = blockIdx.x * 4 + (threadIdx.x >> 6);
    int j   = threadIdx.x & 63;
    if (row < N_NODES) {
        float acc = 0.f;
#pragma unroll
        for (int k = 0; k < F_IN; ++k) acc += x[row * F_IN + k] * sW[k * H + j];
        hw[row * H + j] = acc;
    }
}

__global__ void k_mm_h(const float* __restrict__ h, const float* __restrict__ W,
                       float* __restrict__ hw) {
    __shared__ float sW[H * H];
    __shared__ float srow[4][H];
    for (int t = threadIdx.x; t < H * H; t += 256) sW[t] = W[t];
    int wi = threadIdx.x >> 6;
    int j  = threadIdx.x & 63;
    int row = blockIdx.x * 4 + wi;
    if (row < N_NODES) srow[wi][j] = h[row * H + j];
    __syncthreads();
    if (row < N_NODES) {
        float acc = 0.f;
#pragma unroll
        for (int k = 0; k < H; ++k) acc += srow[wi][k] * sW[k * H + j];
        hw[row * H + j] = acc;
    }
}

// ---------------- fused GCN aggregate: self + gather + bias + tanh ----------------

__global__ void k_gather(const float* __restrict__ hw, const int* __restrict__ off,
                         const int* __restrict__ csr_src, const float* __restrict__ csr_norm,
                         const float* __restrict__ dis, const float* __restrict__ b,
                         float* __restrict__ hout) {
    int wi = threadIdx.x >> 6, j = threadIdx.x & 63;
    int node = blockIdx.x * 4 + wi;
    if (node >= N_NODES) return;
    int beg = off[node], end = off[node + 1];
    float d = dis[node];
    float acc = hw[node * H + j] * d * d;
    int e = beg;
    for (; e + 3 < end; e += 4) {
        int   s0 = csr_src[e],     s1 = csr_src[e + 1];
        int   s2 = csr_src[e + 2], s3 = csr_src[e + 3];
        float n0 = csr_norm[e],     n1 = csr_norm[e + 1];
        float n2 = csr_norm[e + 2], n3 = csr_norm[e + 3];
        float v0 = hw[s0 * H + j], v1 = hw[s1 * H + j];
        float v2 = hw[s2 * H + j], v3 = hw[s3 * H + j];
        acc += v0 * n0 + v1 * n1 + v2 * n2 + v3 * n3;
    }
    for (; e < end; ++e) acc += hw[csr_src[e] * H + j] * csr_norm[e];
    hout[node * H + j] = tanhf(acc + b[j]);
}

// ---------------- fused MLP + graph pool ----------------

__global__ void k_mlp(const float* __restrict__ h, const int* __restrict__ batch,
                      const float* __restrict__ fc1w, const float* __restrict__ fc1b,
                      const float* __restrict__ fc2w, const float* __restrict__ fc2b,
                      const float* __restrict__ fc3w, const float* __restrict__ fc3b,
                      float* __restrict__ sums) {
    __shared__ float s1[H * H];
    __shared__ float s2[H * 32];
    __shared__ float s3[32];
    __shared__ float sb1[H];
    __shared__ float sb2[32];
    __shared__ float srow[4][H];
    __shared__ float s1out[4][H];

    for (int t = threadIdx.x; t < H * H; t += 256) s1[t] = fc1w[t];
    for (int t = threadIdx.x; t < H * 32; t += 256) s2[t] = fc2w[t];
    if (threadIdx.x < 32) s3[threadIdx.x] = fc3w[threadIdx.x];
    if (threadIdx.x < H)  sb1[threadIdx.x] = fc1b[threadIdx.x];
    if (threadIdx.x < 32) sb2[threadIdx.x] = fc2b[threadIdx.x];
    __syncthreads();

    int wi   = threadIdx.x >> 6;
    int j    = threadIdx.x & 63;
    int node = blockIdx.x * 4 + wi;
    if (node >= N_NODES) return;

    srow[wi][j] = h[node * H + j];

    float a1 = 0.f;
#pragma unroll
    for (int k = 0; k < H; ++k) a1 += srow[wi][k] * s1[k * H + j];
    a1 = tanhf(a1 + sb1[j]);
    s1out[wi][j] = a1;

    float a2 = 0.f;
    if (j < 32) {
#pragma unroll
        for (int k = 0; k < H; ++k) a2 += s1out[wi][k] * s2[k * 32 + j];
        a2 = tanhf(a2 + sb2[j]);
        a2 *= s3[j];
    }
    for (int off = 16; off > 0; off >>= 1) a2 += __shfl_down(a2, off, 32);
    if (j == 0) {
        float val = a2 + fc3b[0];
        atomicAdd(&sums[batch[node]], val);
    }
}

// ---------------- readout ----------------

__global__ void k_util(const float* __restrict__ sums, const float* __restrict__ cnt,
                       float* __restrict__ out_util) {
    int g = blockIdx.x * blockDim.x + threadIdx.x;
    if (g < N_GRAPHS) out_util[g] = sums[g] / fmaxf(cnt[g], 1.0f);
}

__global__ void k_pairs(const float* __restrict__ u, const int* __restrict__ ia,
                        const int* __restrict__ ib, float* __restrict__ out) {
    int p = blockIdx.x * blockDim.x + threadIdx.x;
    if (p < N_PAIRS) {
        float d = u[ib[p]] - u[ia[p]];
        out[p] = 1.0f / (1.0f + expf(-d));
    }
}

// ---------------- launch ----------------

extern "C" void kernel_launch(void* const* d_in, const int* in_sizes, int n_in,
                              void* d_out, int out_size, void* d_ws, size_t ws_size,
                              hipStream_t stream) {
    const float* x     = (const float*)d_in[0];
    const int*   ei    = (const int*)d_in[1];
    const int*   batch = (const int*)d_in[2];
    const int*   idx_a = (const int*)d_in[3];
    const int*   idx_b = (const int*)d_in[4];
    const float* W_in  = (const float*)d_in[5];
    const float* b_in  = (const float*)d_in[6];
    const float* W_h   = (const float*)d_in[7];
    const float* b_h   = (const float*)d_in[8];
    const float* W_out = (const float*)d_in[9];
    const float* b_out = (const float*)d_in[10];
    const float* fc1_w = (const float*)d_in[11];
    const float* fc1_b = (const float*)d_in[12];
    const float* fc2_w = (const float*)d_in[13];
    const float* fc2_b = (const float*)d_in[14];
    const float* fc3_w = (const float*)d_in[15];
    const float* fc3_b = (const float*)d_in[16];

    const int* src = ei;
    const int* dst = ei + N_EDGES;

    char* wsb = (char*)d_ws;
    float* dis      = (float*)wsb;  wsb += N_NODES * 4;
    float* cnt      = (float*)wsb;  wsb += N_GRAPHS * 4;
    float* sums     = (float*)wsb;  wsb += N_GRAPHS * 4;
    float* hw       = (float*)wsb;  wsb += (size_t)N_NODES * H * 4;
    float* h        = (float*)wsb;  wsb += (size_t)N_NODES * H * 4;
    int*   degi     = (int*)wsb;    wsb += N_NODES * 4;
    int*   offs     = (int*)wsb;    wsb += (N_NODES + 1) * 4;
    int*   cur      = (int*)wsb;    wsb += N_NODES * 4;
    int*   chunksum = (int*)wsb;    wsb += NCHUNK * 4;
    int*   chunkbase= (int*)wsb;    wsb += NCHUNK * 4;
    int*   csr_src  = (int*)wsb;    wsb += (size_t)N_EDGES * 4;
    float* csr_norm = (float*)wsb;  wsb += (size_t)N_EDGES * 4;

    float* out_pairs = (float*)d_out;
    float* out_util  = out_pairs + N_PAIRS;

    hipMemsetAsync(degi, 0, N_NODES  * sizeof(int),   stream);
    hipMemsetAsync(cnt,  0, N_GRAPHS * sizeof(float), stream);
    hipMemsetAsync(sums, 0, N_GRAPHS * sizeof(float), stream);

    dim3 blk(256);
    k_deg<<<(N_EDGES + 255) / 256, blk, 0, stream>>>(dst, degi);
    k_dis<<<(N_NODES + 255) / 256, blk, 0, stream>>>(degi, dis);
    k_cnt<<<(N_NODES + 255) / 256, blk, 0, stream>>>(batch, cnt);

    k_chunksum<<<NCHUNK, blk, 0, stream>>>(degi, chunksum);
    k_scanchunks<<<1, 64, 0, stream>>>(chunksum, chunkbase, offs);
    k_scan<<<NCHUNK, blk, 0, stream>>>(degi, chunkbase, offs, cur);
    k_fill<<<(N_EDGES + 255) / 256, blk, 0, stream>>>(src, dst, dis, cur, csr_src, csr_norm);

    const int row_blocks = (N_NODES + 3) / 4;

    // layer 1 (F_IN -> H)
    k_mm_in<<<row_blocks, blk, 0, stream>>>(x, W_in, hw);
    k_gather<<<row_blocks, blk, 0, stream>>>(hw, offs, csr_src, csr_norm, dis, b_in, h);

    // layers 2..3 (H -> H, shared weights)
    for (int l = 0; l < 2; ++l) {
        k_mm_h<<<row_blocks, blk, 0, stream>>>(h, W_h, hw);
        k_gather<<<row_blocks, blk, 0, stream>>>(hw, offs, csr_src, csr_norm, dis, b_h, h);
    }

    // layer 4 (H -> H, W_out)
    k_mm_h<<<row_blocks, blk, 0, stream>>>(h, W_out, hw);
    k_gather<<<row_blocks, blk, 0, stream>>>(hw, offs, csr_src, csr_norm, dis, b_out, h);

    // MLP + pool
    k_mlp<<<row_blocks, blk, 0, stream>>>(h, batch, fc1_w, fc1_b, fc2_w, fc2_b,
                                          fc3_w, fc3_b, sums);
    k_util<<<(N_GRAPHS + 255) / 256, blk, 0, stream>>>(sums, cnt, out_util);
    k_pairs<<<(N_PAIRS + 255) / 256, blk, 0, stream>>>(out_util, idx_a, idx_b, out_pairs);
}

// Round 3
// 401.576 us; speedup vs baseline: 2.4146x; 1.0731x over previous
//
#include <hip/hip_runtime.h>
#include <math.h>

#define N_NODES  50000
#define N_EDGES  800000
#define N_GRAPHS 5000
#define N_PAIRS  4096
#define F_IN     9
#define H        64
#define NCHUNK   49   // ceil(50000/1024)

// ---------------- degree / norm / counts ----------------

__global__ void k_deg(const int* __restrict__ dst, int* __restrict__ degi) {
    int e = blockIdx.x * blockDim.x + threadIdx.x;
    if (e < N_EDGES) atomicAdd(&degi[dst[e]], 1);
}

__global__ void k_dis(const int* __restrict__ degi, float* __restrict__ dis) {
    int i = blockIdx.x * blockDim.x + threadIdx.x;
    if (i < N_NODES) dis[i] = rsqrtf((float)degi[i] + 1.0f);
}

__global__ void k_cnt(const int* __restrict__ batch, float* __restrict__ cnt) {
    int i = blockIdx.x * blockDim.x + threadIdx.x;
    if (i < N_NODES) atomicAdd(&cnt[batch[i]], 1.0f);
}

// ---------------- CSR build: scan + fill ----------------

__global__ void k_chunksum(const int* __restrict__ degi, int* __restrict__ chunksum) {
    __shared__ int wsum[4];
    int t = threadIdx.x, lane = t & 63, wi = t >> 6;
    int base_i = blockIdx.x * 1024 + t * 4;
    int s = 0;
#pragma unroll
    for (int k = 0; k < 4; ++k) {
        int i = base_i + k;
        if (i < N_NODES) s += degi[i];
    }
    for (int o = 32; o > 0; o >>= 1) s += __shfl_down(s, o, 64);
    if (lane == 0) wsum[wi] = s;
    __syncthreads();
    if (t == 0) chunksum[blockIdx.x] = wsum[0] + wsum[1] + wsum[2] + wsum[3];
}

__global__ void k_scanchunks(const int* __restrict__ chunksum, int* __restrict__ chunkbase,
                             int* __restrict__ off) {
    int lane = threadIdx.x;
    int v = (lane < NCHUNK) ? chunksum[lane] : 0;
    int inc = v;
    for (int o = 1; o < 64; o <<= 1) {
        int u = __shfl_up(inc, o, 64);
        if (lane >= o) inc += u;
    }
    if (lane < NCHUNK) chunkbase[lane] = inc - v;
    if (lane == 0) off[N_NODES] = N_EDGES;
}

__global__ void k_scan(const int* __restrict__ degi, const int* __restrict__ chunkbase,
                       int* __restrict__ off, int* __restrict__ cur) {
    __shared__ int wsum[4];
    int t = threadIdx.x, lane = t & 63, wi = t >> 6;
    int base_i = blockIdx.x * 1024 + t * 4;
    int v[4];
    int s = 0;
#pragma unroll
    for (int k = 0; k < 4; ++k) {
        int i = base_i + k;
        v[k] = (i < N_NODES) ? degi[i] : 0;
        s += v[k];
    }
    int inc = s;
    for (int o = 1; o < 64; o <<= 1) {
        int u = __shfl_up(inc, o, 64);
        if (lane >= o) inc += u;
    }
    if (lane == 63) wsum[wi] = inc;
    __syncthreads();
    int wbase = 0;
    for (int w = 0; w < 4; ++w) if (w < wi) wbase += wsum[w];
    int ex = chunkbase[blockIdx.x] + wbase + inc - s;
#pragma unroll
    for (int k = 0; k < 4; ++k) {
        int i = base_i + k;
        if (i < N_NODES) { off[i] = ex; cur[i] = ex; }
        ex += v[k];
    }
}

__global__ void k_fill(const int* __restrict__ src, const int* __restrict__ dst,
                       const float* __restrict__ dis, int* __restrict__ cur,
                       int* __restrict__ csr_src, float* __restrict__ csr_norm) {
    int e = blockIdx.x * blockDim.x + threadIdx.x;
    if (e < N_EDGES) {
        int s = src[e], d = dst[e];
        int pos = atomicAdd(&cur[d], 1);
        csr_src[pos] = s;
        csr_norm[pos] = dis[s] * dis[d];
    }
}

// ---------------- layer 1: aggregate x (9-wide), then fused mm+bias+tanh ----------------

// 16-lane group per node, lanes j<9 active. 16 nodes per 256-block.
__global__ void k_agg9(const float* __restrict__ x, const int* __restrict__ off,
                       const int* __restrict__ csr_src, const float* __restrict__ csr_norm,
                       const float* __restrict__ dis, float* __restrict__ ax) {
    int g = threadIdx.x >> 4;
    int j = threadIdx.x & 15;
    int node = blockIdx.x * 16 + g;
    if (node >= N_NODES || j >= F_IN) return;
    int beg = off[node], end = off[node + 1];
    float d = dis[node];
    float acc = x[node * F_IN + j] * d * d;
    int e = beg;
    for (; e + 1 < end; e += 2) {
        int   s0 = csr_src[e],  s1 = csr_src[e + 1];
        float n0 = csr_norm[e], n1 = csr_norm[e + 1];
        acc += x[s0 * F_IN + j] * n0 + x[s1 * F_IN + j] * n1;
    }
    if (e < end) acc += x[csr_src[e] * F_IN + j] * csr_norm[e];
    ax[node * F_IN + j] = acc;
}

// ax (N,9) @ W (9,64) + b, tanh -> h. 16 rows per 256-block (4/wave).
__global__ void k_mm_in(const float* __restrict__ ax, const float* __restrict__ W,
                        const float* __restrict__ b, float* __restrict__ h) {
    __shared__ float sW[F_IN * H];
    __shared__ float sb[H];
    for (int t = threadIdx.x; t < F_IN * H; t += 256) sW[t] = W[t];
    if (threadIdx.x < H) sb[threadIdx.x] = b[threadIdx.x];
    __syncthreads();
    int wi = threadIdx.x >> 6, j = threadIdx.x & 63;
    for (int r = 0; r < 4; ++r) {
        int row = blockIdx.x * 16 + wi * 4 + r;
        if (row >= N_NODES) break;
        float acc = 0.f;
#pragma unroll
        for (int k = 0; k < F_IN; ++k) acc += ax[row * F_IN + k] * sW[k * H + j];
        h[row * H + j] = tanhf(acc + sb[j]);
    }
}

// ---------------- dense matmul H->H: 32 rows per block ----------------

__global__ void k_mm_h(const float* __restrict__ h, const float* __restrict__ W,
                       float* __restrict__ hw) {
    __shared__ float sW[H * H];
    __shared__ float srow[4][H];
    for (int t = threadIdx.x; t < H * H; t += 256) sW[t] = W[t];
    __syncthreads();
    int wi = threadIdx.x >> 6, j = threadIdx.x & 63;
    int base = blockIdx.x * 32 + wi * 8;
    for (int r = 0; r < 8; ++r) {
        int row = base + r;
        if (row >= N_NODES) break;
        srow[wi][j] = h[row * H + j];   // wave-local: no barrier needed
        float acc = 0.f;
#pragma unroll
        for (int k = 0; k < H; ++k) acc += srow[wi][k] * sW[k * H + j];
        hw[row * H + j] = acc;
    }
}

// ---------------- fused GCN aggregate: self + gather + bias + tanh ----------------

__global__ void k_gather(const float* __restrict__ hw, const int* __restrict__ off,
                         const int* __restrict__ csr_src, const float* __restrict__ csr_norm,
                         const float* __restrict__ dis, const float* __restrict__ b,
                         float* __restrict__ hout) {
    int wi = threadIdx.x >> 6, j = threadIdx.x & 63;
    int node = blockIdx.x * 4 + wi;
    if (node >= N_NODES) return;
    int beg = off[node], end = off[node + 1];
    float d = dis[node];
    float acc = hw[node * H + j] * d * d;
    int e = beg;
    for (; e + 3 < end; e += 4) {
        int   s0 = csr_src[e],     s1 = csr_src[e + 1];
        int   s2 = csr_src[e + 2], s3 = csr_src[e + 3];
        float n0 = csr_norm[e],     n1 = csr_norm[e + 1];
        float n2 = csr_norm[e + 2], n3 = csr_norm[e + 3];
        float v0 = hw[s0 * H + j], v1 = hw[s1 * H + j];
        float v2 = hw[s2 * H + j], v3 = hw[s3 * H + j];
        acc += v0 * n0 + v1 * n1 + v2 * n2 + v3 * n3;
    }
    for (; e < end; ++e) acc += hw[csr_src[e] * H + j] * csr_norm[e];
    hout[node * H + j] = tanhf(acc + b[j]);
}

// ---------------- fused MLP + graph pool: 64 nodes per block ----------------

__global__ void k_mlp(const float* __restrict__ h, const int* __restrict__ batch,
                      const float* __restrict__ fc1w, const float* __restrict__ fc1b,
                      const float* __restrict__ fc2w, const float* __restrict__ fc2b,
                      const float* __restrict__ fc3w, const float* __restrict__ fc3b,
                      float* __restrict__ sums) {
    __shared__ float s1[H * H];
    __shared__ float s2[H * 32];
    __shared__ float s3[32];
    __shared__ float sb1[H];
    __shared__ float sb2[32];
    __shared__ float srow[4][H];
    __shared__ float s1out[4][H];

    for (int t = threadIdx.x; t < H * H; t += 256) s1[t] = fc1w[t];
    for (int t = threadIdx.x; t < H * 32; t += 256) s2[t] = fc2w[t];
    if (threadIdx.x < 32) s3[threadIdx.x] = fc3w[threadIdx.x];
    if (threadIdx.x < H)  sb1[threadIdx.x] = fc1b[threadIdx.x];
    if (threadIdx.x < 32) sb2[threadIdx.x] = fc2b[threadIdx.x];
    __syncthreads();

    int wi = threadIdx.x >> 6, j = threadIdx.x & 63;
    float b3 = fc3b[0];

    for (int it = 0; it < 16; ++it) {
        int node = blockIdx.x * 64 + wi * 16 + it;
        if (node >= N_NODES) break;

        srow[wi][j] = h[node * H + j];   // wave-local

        float a1 = 0.f;
#pragma unroll
        for (int k = 0; k < H; ++k) a1 += srow[wi][k] * s1[k * H + j];
        a1 = tanhf(a1 + sb1[j]);
        s1out[wi][j] = a1;               // wave-local

        float a2 = 0.f;
        if (j < 32) {
#pragma unroll
            for (int k = 0; k < H; ++k) a2 += s1out[wi][k] * s2[k * 32 + j];
            a2 = tanhf(a2 + sb2[j]);
            a2 *= s3[j];
        }
        for (int off = 16; off > 0; off >>= 1) a2 += __shfl_down(a2, off, 32);
        if (j == 0) atomicAdd(&sums[batch[node]], a2 + b3);
    }
}

// ---------------- readout ----------------

__global__ void k_util(const float* __restrict__ sums, const float* __restrict__ cnt,
                       float* __restrict__ out_util) {
    int g = blockIdx.x * blockDim.x + threadIdx.x;
    if (g < N_GRAPHS) out_util[g] = sums[g] / fmaxf(cnt[g], 1.0f);
}

__global__ void k_pairs(const float* __restrict__ u, const int* __restrict__ ia,
                        const int* __restrict__ ib, float* __restrict__ out) {
    int p = blockIdx.x * blockDim.x + threadIdx.x;
    if (p < N_PAIRS) {
        float d = u[ib[p]] - u[ia[p]];
        out[p] = 1.0f / (1.0f + expf(-d));
    }
}

// ---------------- launch ----------------

extern "C" void kernel_launch(void* const* d_in, const int* in_sizes, int n_in,
                              void* d_out, int out_size, void* d_ws, size_t ws_size,
                              hipStream_t stream) {
    const float* x     = (const float*)d_in[0];
    const int*   ei    = (const int*)d_in[1];
    const int*   batch = (const int*)d_in[2];
    const int*   idx_a = (const int*)d_in[3];
    const int*   idx_b = (const int*)d_in[4];
    const float* W_in  = (const float*)d_in[5];
    const float* b_in  = (const float*)d_in[6];
    const float* W_h   = (const float*)d_in[7];
    const float* b_h   = (const float*)d_in[8];
    const float* W_out = (const float*)d_in[9];
    const float* b_out = (const float*)d_in[10];
    const float* fc1_w = (const float*)d_in[11];
    const float* fc1_b = (const float*)d_in[12];
    const float* fc2_w = (const float*)d_in[13];
    const float* fc2_b = (const float*)d_in[14];
    const float* fc3_w = (const float*)d_in[15];
    const float* fc3_b = (const float*)d_in[16];

    const int* src = ei;
    const int* dst = ei + N_EDGES;

    char* wsb = (char*)d_ws;
    float* dis      = (float*)wsb;  wsb += N_NODES * 4;
    float* cnt      = (float*)wsb;  wsb += N_GRAPHS * 4;
    float* sums     = (float*)wsb;  wsb += N_GRAPHS * 4;
    float* ax       = (float*)wsb;  wsb += (size_t)N_NODES * F_IN * 4;
    float* hw       = (float*)wsb;  wsb += (size_t)N_NODES * H * 4;
    float* h        = (float*)wsb;  wsb += (size_t)N_NODES * H * 4;
    int*   degi     = (int*)wsb;    wsb += N_NODES * 4;
    int*   offs     = (int*)wsb;    wsb += (N_NODES + 1) * 4;
    int*   cur      = (int*)wsb;    wsb += N_NODES * 4;
    int*   chunksum = (int*)wsb;    wsb += NCHUNK * 4;
    int*   chunkbase= (int*)wsb;    wsb += NCHUNK * 4;
    int*   csr_src  = (int*)wsb;    wsb += (size_t)N_EDGES * 4;
    float* csr_norm = (float*)wsb;  wsb += (size_t)N_EDGES * 4;

    float* out_pairs = (float*)d_out;
    float* out_util  = out_pairs + N_PAIRS;

    hipMemsetAsync(degi, 0, N_NODES  * sizeof(int),   stream);
    hipMemsetAsync(cnt,  0, N_GRAPHS * sizeof(float), stream);
    hipMemsetAsync(sums, 0, N_GRAPHS * sizeof(float), stream);

    dim3 blk(256);
    k_deg<<<(N_EDGES + 255) / 256, blk, 0, stream>>>(dst, degi);
    k_dis<<<(N_NODES + 255) / 256, blk, 0, stream>>>(degi, dis);
    k_cnt<<<(N_NODES + 255) / 256, blk, 0, stream>>>(batch, cnt);

    k_chunksum<<<NCHUNK, blk, 0, stream>>>(degi, chunksum);
    k_scanchunks<<<1, 64, 0, stream>>>(chunksum, chunkbase, offs);
    k_scan<<<NCHUNK, blk, 0, stream>>>(degi, chunkbase, offs, cur);
    k_fill<<<(N_EDGES + 255) / 256, blk, 0, stream>>>(src, dst, dis, cur, csr_src, csr_norm);

    // layer 1: aggregate x first (9-wide), then fused mm+bias+tanh
    k_agg9<<<(N_NODES + 15) / 16, blk, 0, stream>>>(x, offs, csr_src, csr_norm, dis, ax);
    k_mm_in<<<(N_NODES + 15) / 16, blk, 0, stream>>>(ax, W_in, b_in, h);

    const int mm_blocks  = (N_NODES + 31) / 32;
    const int gat_blocks = (N_NODES + 3) / 4;

    // layers 2..3 (H -> H, shared weights)
    for (int l = 0; l < 2; ++l) {
        k_mm_h<<<mm_blocks, blk, 0, stream>>>(h, W_h, hw);
        k_gather<<<gat_blocks, blk, 0, stream>>>(hw, offs, csr_src, csr_norm, dis, b_h, h);
    }

    // layer 4 (H -> H, W_out)
    k_mm_h<<<mm_blocks, blk, 0, stream>>>(h, W_out, hw);
    k_gather<<<gat_blocks, blk, 0, stream>>>(hw, offs, csr_src, csr_norm, dis, b_out, h);

    // MLP + pool
    k_mlp<<<(N_NODES + 63) / 64, blk, 0, stream>>>(h, batch, fc1_w, fc1_b, fc2_w, fc2_b,
                                                   fc3_w, fc3_b, sums);
    k_util<<<(N_GRAPHS + 255) / 256, blk, 0, stream>>>(sums, cnt, out_util);
    k_pairs<<<(N_PAIRS + 255) / 256, blk, 0, stream>>>(out_util, idx_a, idx_b, out_pairs);
}

// Round 4
// 300.577 us; speedup vs baseline: 3.2260x; 1.3360x over previous
//
#include <hip/hip_runtime.h>
#include <math.h>

#define N_NODES  50000
#define N_EDGES  800000
#define N_GRAPHS 5000
#define N_PAIRS  4096
#define F_IN     9
#define H        64
#define NCHUNK   49   // ceil(50000/1024)
#define WPAD     68   // transposed-weight row stride: 272B = 16B-aligned, even bank spread

__device__ __forceinline__ float fast_tanh(float x) {
    float e = __expf(-2.0f * fabsf(x));
    float t = __fdividef(1.0f - e, 1.0f + e);
    return copysignf(t, x);
}

// ---------------- degree + graph counts (merged) ----------------

__global__ void k_deg_cnt(const int* __restrict__ dst, const int* __restrict__ batch,
                          int* __restrict__ degi, float* __restrict__ cnt) {
    int i = blockIdx.x * blockDim.x + threadIdx.x;
    if (i < N_EDGES) atomicAdd(&degi[dst[i]], 1);
    if (i < N_NODES) atomicAdd(&cnt[batch[i]], 1.0f);
}

// ---------------- dis + chunk sums (merged) ----------------

__global__ void k_dis_chunksum(const int* __restrict__ degi, float* __restrict__ dis,
                               int* __restrict__ chunksum) {
    __shared__ int wsum[4];
    int t = threadIdx.x, lane = t & 63, wi = t >> 6;
    int base_i = blockIdx.x * 1024 + t * 4;
    int s = 0;
#pragma unroll
    for (int k = 0; k < 4; ++k) {
        int i = base_i + k;
        if (i < N_NODES) {
            int dg = degi[i];
            s += dg;
            dis[i] = rsqrtf((float)dg + 1.0f);
        }
    }
    for (int o = 32; o > 0; o >>= 1) s += __shfl_down(s, o, 64);
    if (lane == 0) wsum[wi] = s;
    __syncthreads();
    if (t == 0) chunksum[blockIdx.x] = wsum[0] + wsum[1] + wsum[2] + wsum[3];
}

__global__ void k_scanchunks(const int* __restrict__ chunksum, int* __restrict__ chunkbase,
                             int* __restrict__ off) {
    int lane = threadIdx.x;
    int v = (lane < NCHUNK) ? chunksum[lane] : 0;
    int inc = v;
    for (int o = 1; o < 64; o <<= 1) {
        int u = __shfl_up(inc, o, 64);
        if (lane >= o) inc += u;
    }
    if (lane < NCHUNK) chunkbase[lane] = inc - v;
    if (lane == 0) off[N_NODES] = N_EDGES;
}

__global__ void k_scan(const int* __restrict__ degi, const int* __restrict__ chunkbase,
                       int* __restrict__ off, int* __restrict__ cur) {
    __shared__ int wsum[4];
    int t = threadIdx.x, lane = t & 63, wi = t >> 6;
    int base_i = blockIdx.x * 1024 + t * 4;
    int v[4];
    int s = 0;
#pragma unroll
    for (int k = 0; k < 4; ++k) {
        int i = base_i + k;
        v[k] = (i < N_NODES) ? degi[i] : 0;
        s += v[k];
    }
    int inc = s;
    for (int o = 1; o < 64; o <<= 1) {
        int u = __shfl_up(inc, o, 64);
        if (lane >= o) inc += u;
    }
    if (lane == 63) wsum[wi] = inc;
    __syncthreads();
    int wbase = 0;
    for (int w = 0; w < 4; ++w) if (w < wi) wbase += wsum[w];
    int ex = chunkbase[blockIdx.x] + wbase + inc - s;
#pragma unroll
    for (int k = 0; k < 4; ++k) {
        int i = base_i + k;
        if (i < N_NODES) { off[i] = ex; cur[i] = ex; }
        ex += v[k];
    }
}

__global__ void k_fill(const int* __restrict__ src, const int* __restrict__ dst,
                       const float* __restrict__ dis, int* __restrict__ cur,
                       int* __restrict__ csr_src, float* __restrict__ csr_norm) {
    int e = blockIdx.x * blockDim.x + threadIdx.x;
    if (e < N_EDGES) {
        int s = src[e], d = dst[e];
        int pos = atomicAdd(&cur[d], 1);
        csr_src[pos] = s;
        csr_norm[pos] = dis[s] * dis[d];
    }
}

// ---------------- layer 1: aggregate x (9-wide), then fused mm+bias+tanh ----------------

__global__ void k_agg9(const float* __restrict__ x, const int* __restrict__ off,
                       const int* __restrict__ csr_src, const float* __restrict__ csr_norm,
                       const float* __restrict__ dis, float* __restrict__ ax) {
    int g = threadIdx.x >> 4;
    int j = threadIdx.x & 15;
    int node = blockIdx.x * 16 + g;
    if (node >= N_NODES || j >= F_IN) return;
    int beg = off[node], end = off[node + 1];
    float d = dis[node];
    float acc = x[node * F_IN + j] * d * d;
    int e = beg;
    for (; e + 1 < end; e += 2) {
        int   s0 = csr_src[e],  s1 = csr_src[e + 1];
        float n0 = csr_norm[e], n1 = csr_norm[e + 1];
        acc += x[s0 * F_IN + j] * n0 + x[s1 * F_IN + j] * n1;
    }
    if (e < end) acc += x[csr_src[e] * F_IN + j] * csr_norm[e];
    ax[node * F_IN + j] = acc;
}

__global__ void k_mm_in(const float* __restrict__ ax, const float* __restrict__ W,
                        const float* __restrict__ b, float* __restrict__ h) {
    __shared__ float sW[F_IN * H];
    __shared__ float sb[H];
    for (int t = threadIdx.x; t < F_IN * H; t += 256) sW[t] = W[t];
    if (threadIdx.x < H) sb[threadIdx.x] = b[threadIdx.x];
    __syncthreads();
    int wi = threadIdx.x >> 6, j = threadIdx.x & 63;
    for (int r = 0; r < 4; ++r) {
        int row = blockIdx.x * 16 + wi * 4 + r;
        if (row >= N_NODES) break;
        float acc = sb[j];
#pragma unroll
        for (int k = 0; k < F_IN; ++k) acc += ax[row * F_IN + k] * sW[k * H + j];
        h[row * H + j] = fast_tanh(acc);
    }
}

// ---------------- fused layer: gather(h) -> @W + b -> tanh ----------------
// 4 waves/block, 8 nodes/wave. Transposed weights in LDS, b128 reads.

__global__ __launch_bounds__(256) void k_gmm(
        const float* __restrict__ hin, const int* __restrict__ off,
        const int* __restrict__ csr_src, const float* __restrict__ csr_norm,
        const float* __restrict__ dis, const float* __restrict__ W,
        const float* __restrict__ b, float* __restrict__ hout) {
    __shared__ float sWt[H][WPAD];   // sWt[j][k] = W[k][j]
    __shared__ float sb[H];
    __shared__ float srow[4][H];
    for (int t = threadIdx.x; t < H * H; t += 256) {
        int k = t >> 6, jx = t & 63;
        sWt[jx][k] = W[t];
    }
    if (threadIdx.x < H) sb[threadIdx.x] = b[threadIdx.x];
    __syncthreads();
    int wi = threadIdx.x >> 6, j = threadIdx.x & 63;
    for (int it = 0; it < 8; ++it) {
        int node = blockIdx.x * 32 + wi * 8 + it;
        if (node >= N_NODES) break;
        int beg = off[node], end = off[node + 1];
        float d = dis[node];
        float acc = hin[node * H + j] * d * d;
        int e = beg;
        for (; e + 3 < end; e += 4) {
            int   s0 = csr_src[e],     s1 = csr_src[e + 1];
            int   s2 = csr_src[e + 2], s3 = csr_src[e + 3];
            float n0 = csr_norm[e],     n1 = csr_norm[e + 1];
            float n2 = csr_norm[e + 2], n3 = csr_norm[e + 3];
            acc += hin[s0 * H + j] * n0 + hin[s1 * H + j] * n1
                 + hin[s2 * H + j] * n2 + hin[s3 * H + j] * n3;
        }
        for (; e < end; ++e) acc += hin[csr_src[e] * H + j] * csr_norm[e];

        srow[wi][j] = acc;          // wave-local write then read: in-order per wave
        float a = sb[j];
#pragma unroll
        for (int kb = 0; kb < H; kb += 4) {
            float4 g4 = *(const float4*)&srow[wi][kb];   // uniform-addr broadcast
            float4 w4 = *(const float4*)&sWt[j][kb];     // per-lane b128
            a += g4.x * w4.x + g4.y * w4.y + g4.z * w4.z + g4.w * w4.w;
        }
        hout[node * H + j] = fast_tanh(a);
    }
}

// ---------------- fused MLP + graph pool ----------------
// fc1 via transposed b128; fc2 split across half-waves; fast tanh.

__global__ __launch_bounds__(256) void k_mlp(
        const float* __restrict__ h, const int* __restrict__ batch,
        const float* __restrict__ fc1w, const float* __restrict__ fc1b,
        const float* __restrict__ fc2w, const float* __restrict__ fc2b,
        const float* __restrict__ fc3w, const float* __restrict__ fc3b,
        float* __restrict__ sums) {
    __shared__ float s1t[H][WPAD];    // s1t[j][k] = fc1w[k*H+j]
    __shared__ float s2t[32][WPAD];   // s2t[j][k] = fc2w[k*32+j]
    __shared__ float s3[32];
    __shared__ float sb1[H];
    __shared__ float sb2[32];
    __shared__ float srow[4][H];
    __shared__ float s1out[4][H];

    for (int t = threadIdx.x; t < H * H; t += 256) {
        int k = t >> 6, jx = t & 63;
        s1t[jx][k] = fc1w[t];
    }
    for (int t = threadIdx.x; t < H * 32; t += 256) {
        int k = t >> 5, jx = t & 31;
        s2t[jx][k] = fc2w[t];
    }
    if (threadIdx.x < 32) s3[threadIdx.x] = fc3w[threadIdx.x];
    if (threadIdx.x < H)  sb1[threadIdx.x] = fc1b[threadIdx.x];
    if (threadIdx.x < 32) sb2[threadIdx.x] = fc2b[threadIdx.x];
    __syncthreads();

    int wi = threadIdx.x >> 6, j = threadIdx.x & 63;
    int jj = j & 31, kb0 = (j >> 5) << 5;
    float b3 = fc3b[0];

    for (int it = 0; it < 8; ++it) {
        int node = blockIdx.x * 32 + wi * 8 + it;
        if (node >= N_NODES) break;

        srow[wi][j] = h[node * H + j];

        float a1 = sb1[j];
#pragma unroll
        for (int kb = 0; kb < H; kb += 4) {
            float4 g4 = *(const float4*)&srow[wi][kb];
            float4 w4 = *(const float4*)&s1t[j][kb];
            a1 += g4.x * w4.x + g4.y * w4.y + g4.z * w4.z + g4.w * w4.w;
        }
        a1 = fast_tanh(a1);
        s1out[wi][j] = a1;

        // fc2: lane j handles column jj = j&31, k-half selected by j>>5
        float a2 = 0.f;
#pragma unroll
        for (int kb = 0; kb < 32; kb += 4) {
            float4 g4 = *(const float4*)&s1out[wi][kb0 + kb];
            float4 w4 = *(const float4*)&s2t[jj][kb0 + kb];
            a2 += g4.x * w4.x + g4.y * w4.y + g4.z * w4.z + g4.w * w4.w;
        }
        a2 += __shfl_xor(a2, 32);             // combine k-halves
        float val = fast_tanh(a2 + sb2[jj]) * s3[jj];
        // reduce over the 32 columns (lanes 0..31; lanes 32..63 are duplicates)
        for (int o = 16; o > 0; o >>= 1) val += __shfl_xor(val, o);
        if (j == 0) atomicAdd(&sums[batch[node]], val + b3);
    }
}

// ---------------- readout: x_util + pairs (merged, independent) ----------------

__global__ void k_finish(const float* __restrict__ sums, const float* __restrict__ cnt,
                         const int* __restrict__ ia, const int* __restrict__ ib,
                         float* __restrict__ out_pairs, float* __restrict__ out_util) {
    int i = blockIdx.x * blockDim.x + threadIdx.x;
    if (i < N_GRAPHS) out_util[i] = sums[i] / fmaxf(cnt[i], 1.0f);
    if (i < N_PAIRS) {
        int a = ia[i], b = ib[i];
        float ua = sums[a] / fmaxf(cnt[a], 1.0f);
        float ub = sums[b] / fmaxf(cnt[b], 1.0f);
        out_pairs[i] = 1.0f / (1.0f + __expf(-(ub - ua)));
    }
}

// ---------------- launch ----------------

extern "C" void kernel_launch(void* const* d_in, const int* in_sizes, int n_in,
                              void* d_out, int out_size, void* d_ws, size_t ws_size,
                              hipStream_t stream) {
    const float* x     = (const float*)d_in[0];
    const int*   ei    = (const int*)d_in[1];
    const int*   batch = (const int*)d_in[2];
    const int*   idx_a = (const int*)d_in[3];
    const int*   idx_b = (const int*)d_in[4];
    const float* W_in  = (const float*)d_in[5];
    const float* b_in  = (const float*)d_in[6];
    const float* W_h   = (const float*)d_in[7];
    const float* b_h   = (const float*)d_in[8];
    const float* W_out = (const float*)d_in[9];
    const float* b_out = (const float*)d_in[10];
    const float* fc1_w = (const float*)d_in[11];
    const float* fc1_b = (const float*)d_in[12];
    const float* fc2_w = (const float*)d_in[13];
    const float* fc2_b = (const float*)d_in[14];
    const float* fc3_w = (const float*)d_in[15];
    const float* fc3_b = (const float*)d_in[16];

    const int* src = ei;
    const int* dst = ei + N_EDGES;

    char* wsb = (char*)d_ws;
    // zero-region (one memset): degi, cnt, sums
    int*   degi     = (int*)wsb;    wsb += N_NODES * 4;
    float* cnt      = (float*)wsb;  wsb += N_GRAPHS * 4;
    float* sums     = (float*)wsb;  wsb += N_GRAPHS * 4;
    float* dis      = (float*)wsb;  wsb += N_NODES * 4;
    float* ax       = (float*)wsb;  wsb += (size_t)N_NODES * F_IN * 4;
    float* h0       = (float*)wsb;  wsb += (size_t)N_NODES * H * 4;
    float* h1       = (float*)wsb;  wsb += (size_t)N_NODES * H * 4;
    int*   offs     = (int*)wsb;    wsb += (N_NODES + 1) * 4;
    int*   cur      = (int*)wsb;    wsb += N_NODES * 4;
    int*   chunksum = (int*)wsb;    wsb += NCHUNK * 4;
    int*   chunkbase= (int*)wsb;    wsb += NCHUNK * 4;
    int*   csr_src  = (int*)wsb;    wsb += (size_t)N_EDGES * 4;
    float* csr_norm = (float*)wsb;  wsb += (size_t)N_EDGES * 4;

    float* out_pairs = (float*)d_out;
    float* out_util  = out_pairs + N_PAIRS;

    hipMemsetAsync(degi, 0, (N_NODES + 2 * N_GRAPHS) * sizeof(int), stream);

    dim3 blk(256);
    k_deg_cnt<<<(N_EDGES + 255) / 256, blk, 0, stream>>>(dst, batch, degi, cnt);
    k_dis_chunksum<<<NCHUNK, blk, 0, stream>>>(degi, dis, chunksum);
    k_scanchunks<<<1, 64, 0, stream>>>(chunksum, chunkbase, offs);
    k_scan<<<NCHUNK, blk, 0, stream>>>(degi, chunkbase, offs, cur);
    k_fill<<<(N_EDGES + 255) / 256, blk, 0, stream>>>(src, dst, dis, cur, csr_src, csr_norm);

    // layer 1: aggregate x (9-wide) then fused mm+bias+tanh
    k_agg9<<<(N_NODES + 15) / 16, blk, 0, stream>>>(x, offs, csr_src, csr_norm, dis, ax);
    k_mm_in<<<(N_NODES + 15) / 16, blk, 0, stream>>>(ax, W_in, b_in, h0);

    const int gmm_blocks = (N_NODES + 31) / 32;
    // layers 2..4: fused gather+matmul+bias+tanh
    k_gmm<<<gmm_blocks, blk, 0, stream>>>(h0, offs, csr_src, csr_norm, dis, W_h, b_h, h1);
    k_gmm<<<gmm_blocks, blk, 0, stream>>>(h1, offs, csr_src, csr_norm, dis, W_h, b_h, h0);
    k_gmm<<<gmm_blocks, blk, 0, stream>>>(h0, offs, csr_src, csr_norm, dis, W_out, b_out, h1);

    // MLP + pool
    k_mlp<<<gmm_blocks, blk, 0, stream>>>(h1, batch, fc1_w, fc1_b, fc2_w, fc2_b,
                                          fc3_w, fc3_b, sums);
    k_finish<<<(N_GRAPHS + 255) / 256, blk, 0, stream>>>(sums, cnt, idx_a, idx_b,
                                                         out_pairs, out_util);
}